// Round 12
// baseline (635.354 us; speedup 1.0000x reference)
//
#include <hip/hip_runtime.h>
#include <hip/hip_fp16.h>
#include <hip/hip_cooperative_groups.h>

namespace cg = cooperative_groups;

// Tri-plane importance-renderer sampling.
// planes: [N=4][P=3][C=32][H=256][W=256] f32
// coords: [N][M=500000][3] f32, directions unused.
// out:    [N][M][C] f32  = mean over P of bilinear samples (zeros padding,
//                          align_corners=False).
// Plane->grid mapping (from inv(_PLANES)): p0:(cx,cy)  p1:(cx,cz)  p2:(cz,cx)
//
// R11 insight: total stuck at 285us = gather(~135) + transpose(~25) + ~110us
// of sort passes AND 8 serial dispatch drains. The sort's algorithmic traffic
// is worth ~8us. R12: ONE cooperative kernel does zero+transpose+hist+scan+
// scatter with grid.sync() between phases, keys/pos held in REGISTERS across
// phases (no kp array, no bins, no compaction). 2 dispatches total.

constexpr int Cc = 32, Hh = 256, Ww = 256, Pp = 3, Nn = 4;
constexpr int HWPIX = Hh * Ww;   // 65536
constexpr int NCO   = 4096;      // 16^3 coarse Morton cells

constexpr int GRID = 1024, BLK = 256;
constexpr int TT   = GRID * BLK;        // 262144 threads
constexpr int NIT  = 2;                 // ceil(M / TT) for M <= 524288

typedef float f32x4 __attribute__((ext_vector_type(4)));

__device__ inline unsigned spread3(unsigned x) {
    x &= 0x3FFu;
    x = (x | (x << 16)) & 0x030000FFu;
    x = (x | (x << 8))  & 0x0300F00Fu;
    x = (x | (x << 4))  & 0x030C30C3u;
    x = (x | (x << 2))  & 0x09249249u;
    return x;
}
// 12-bit Morton key from 4 bits/axis.
__device__ inline unsigned coarse_key(float cx, float cy, float cz) {
    const int a = min(max((int)((cx + 1.0f) * 8.0f), 0), 15);
    const int b = min(max((int)((cy + 1.0f) * 8.0f), 0), 15);
    const int c = min(max((int)((cz + 1.0f) * 8.0f), 0), 15);
    return spread3((unsigned)a) | (spread3((unsigned)b) << 1) | (spread3((unsigned)c) << 2);
}

// ---------------------------------------------------------------------------
// Cooperative fused prep: zero + transpose(f32 CHW -> fp16 HWC) + key/hist +
// scan + dense scatter. cnt[] is counts after A, exclusive bases after B.
// ---------------------------------------------------------------------------
__global__ __launch_bounds__(256) void fused_prep(
    const float* __restrict__ planes, const float* __restrict__ coords,
    __half* __restrict__ tp, unsigned* __restrict__ cnt,
    unsigned* __restrict__ idx, int M)
{
    __shared__ float lds[Cc * 129];            // 16.5 KB; reused by scan
    const int tid = blockIdx.x * BLK + threadIdx.x;
    const int t   = threadIdx.x;

    // Phase 0a: zero the 4*4096 cell counters.
    for (int i = tid; i < Nn * NCO; i += TT) cnt[i] = 0u;

    // Phase 0b: transpose, grid-stride over 128-pixel tiles (6144 tiles).
    const int ntiles = Nn * Pp * (HWPIX / 128);
    for (int tile = blockIdx.x; tile < ntiles; tile += GRID) {
        const int slice = tile / (HWPIX / 128);
        const int pix0  = (tile - slice * (HWPIX / 128)) * 128;
        __syncthreads();                       // LDS reuse across iterations
        const int p = t & 127, half = t >> 7;
        const float* src = planes + (size_t)slice * Cc * HWPIX + pix0 + p;
        #pragma unroll
        for (int c16 = 0; c16 < 16; ++c16) {
            const int c = half * 16 + c16;
            lds[c * 129 + p] = src[(size_t)c * HWPIX];
        }
        __syncthreads();
        uint4* dst = reinterpret_cast<uint4*>(
            tp + (size_t)slice * HWPIX * Cc + (size_t)pix0 * Cc);
        #pragma unroll
        for (int k = 0; k < 2; ++k) {
            const int id  = k * 256 + t;
            const int pix = id >> 2;           // 4 uint4 per pixel
            const int c0  = (id & 3) * 8;      // 8 channels per uint4
            unsigned r[4];
            #pragma unroll
            for (int j = 0; j < 4; ++j) {
                const __half h0 = __float2half(lds[(c0 + 2 * j + 0) * 129 + pix]);
                const __half h1 = __float2half(lds[(c0 + 2 * j + 1) * 129 + pix]);
                r[j] = (unsigned)__half_as_ushort(h0)
                     | ((unsigned)__half_as_ushort(h1) << 16);
            }
            dst[id] = make_uint4(r[0], r[1], r[2], r[3]);
        }
    }

    cg::this_grid().sync();

    // Phase A: key + per-cell position via atomicAdd; keep packed in regs.
    // pos < M < 2^20, key < 2^12 -> key | pos<<12 fits 32b.
    unsigned kp[Nn][NIT];
    #pragma unroll
    for (int n = 0; n < Nn; ++n) {
        #pragma unroll
        for (int it = 0; it < NIT; ++it) {
            const int m = tid + it * TT;
            unsigned v = 0xFFFFFFFFu;
            if (m < M) {
                const float* cp = coords + ((size_t)n * M + m) * 3;
                const unsigned k = coarse_key(cp[0], cp[1], cp[2]);
                const unsigned pos = atomicAdd(&cnt[n * NCO + k], 1u);
                v = k | (pos << 12);
            }
            kp[n][it] = v;
        }
    }

    cg::this_grid().sync();

    // Phase B: per-n exclusive scan of cnt[n][0..4096). Blocks 0..3 only.
    if (blockIdx.x < Nn) {
        unsigned* h = cnt + blockIdx.x * NCO;
        unsigned* slds = reinterpret_cast<unsigned*>(lds);
        unsigned v[16];
        unsigned s = 0;
        #pragma unroll
        for (int i = 0; i < 16; ++i) { v[i] = h[t * 16 + i]; s += v[i]; }
        slds[t] = s;
        __syncthreads();
        for (int d = 1; d < 256; d <<= 1) {
            const unsigned add = (t >= d) ? slds[t - d] : 0u;
            __syncthreads();
            slds[t] += add;
            __syncthreads();
        }
        unsigned b = (t > 0) ? slds[t - 1] : 0u;
        #pragma unroll
        for (int i = 0; i < 16; ++i) { const unsigned tmp = v[i]; h[t * 16 + i] = b; b += tmp; }
    }

    cg::this_grid().sync();

    // Phase C: dense scatter from registers. idx window 2MB/n, L2-resident.
    #pragma unroll
    for (int n = 0; n < Nn; ++n) {
        #pragma unroll
        for (int it = 0; it < NIT; ++it) {
            const int m = tid + it * TT;
            if (m < M) {
                const unsigned v   = kp[n][it];
                const unsigned k   = v & 0xFFFu;
                const unsigned pos = v >> 12;
                idx[(size_t)n * M + cnt[n * NCO + k] + pos] = (unsigned)m;
            }
        }
    }
}

// ---------------------------------------------------------------------------
// Gather in Morton order (R8/R11 proven body). FOUR lanes per sample, 8 fp16
// channels each (one uint4 per corner). Per-plane packed __hfma2, cross-plane
// f32. Non-temporal output stores. Bijective XCD-chunked swizzle.
// ---------------------------------------------------------------------------
__global__ __launch_bounds__(256) void triplane_gather4h(
    const __half* __restrict__ tp, const unsigned* __restrict__ idx,
    const float* __restrict__ coords, float* __restrict__ out,
    int M, int gx, int nwg)
{
    int bid = blockIdx.x;
    {   // bijective chunked XCD swizzle (m204 form)
        const int q = nwg >> 3, r = nwg & 7;
        const int xcd = bid & 7, i = bid >> 3;
        bid = (xcd < r ? xcd * (q + 1) : r * (q + 1) + (xcd - r) * q) + i;
    }
    const int n  = bid / gx;
    const int bx = bid - n * gx;
    const int gid  = bx * 256 + threadIdx.x;
    const int s    = gid >> 2;
    const int quad = gid & 3;            // 8-channel group
    if (s >= M) return;

    const int m = (int)idx[(size_t)n * M + s];
    const float* cp = coords + ((size_t)n * M + m) * 3;
    const float cx = cp[0], cy = cp[1], cz = cp[2];

    const uint4* addr[12];
    __half2 wh[12];

    #pragma unroll
    for (int p = 0; p < 3; ++p) {
        const float gxc = (p == 2) ? cz : cx;
        const float gyc = (p == 0) ? cy : ((p == 1) ? cz : cx);
        // exact reference op order: ((g+1)*S - 1) * 0.5
        const float x = ((gxc + 1.0f) * 256.0f - 1.0f) * 0.5f;
        const float y = ((gyc + 1.0f) * 256.0f - 1.0f) * 0.5f;
        const float x0f = floorf(x), y0f = floorf(y);
        const float wx = x - x0f, wy = y - y0f;
        const int x0 = (int)x0f, y0 = (int)y0f;
        const int x1 = x0 + 1,   y1 = y0 + 1;
        const bool vx0 = (unsigned)x0 < 256u;
        const bool vx1 = (unsigned)x1 < 256u;
        const bool vy0 = (unsigned)y0 < 256u;
        const bool vy1 = (unsigned)y1 < 256u;
        const int cx0 = min(max(x0, 0), 255), cx1 = min(max(x1, 0), 255);
        const int cy0 = min(max(y0, 0), 255), cy1 = min(max(y1, 0), 255);

        const float w00 = ((vx0 && vy0) ? 1.f : 0.f) * (1.f - wx) * (1.f - wy);
        const float w10 = ((vx1 && vy0) ? 1.f : 0.f) * wx * (1.f - wy);
        const float w01 = ((vx0 && vy1) ? 1.f : 0.f) * (1.f - wx) * wy;
        const float w11 = ((vx1 && vy1) ? 1.f : 0.f) * wx * wy;
        wh[p * 4 + 0] = __float2half2_rn(w00);
        wh[p * 4 + 1] = __float2half2_rn(w10);
        wh[p * 4 + 2] = __float2half2_rn(w01);
        wh[p * 4 + 3] = __float2half2_rn(w11);

        // pixel record = 32 halves = 4 uint4; lane reads uint4 #quad.
        const uint4* base = reinterpret_cast<const uint4*>(
            tp + (size_t)(n * 3 + p) * HWPIX * Cc);
        addr[p * 4 + 0] = base + (size_t)((cy0 << 8) + cx0) * 4 + quad;
        addr[p * 4 + 1] = base + (size_t)((cy0 << 8) + cx1) * 4 + quad;
        addr[p * 4 + 2] = base + (size_t)((cy1 << 8) + cx0) * 4 + quad;
        addr[p * 4 + 3] = base + (size_t)((cy1 << 8) + cx1) * 4 + quad;
    }

    // Issue all 12 independent 16B loads.
    uint4 rv[12];
    #pragma unroll
    for (int j = 0; j < 12; ++j) rv[j] = *addr[j];

    float accx[8];
    #pragma unroll
    for (int i = 0; i < 8; ++i) accx[i] = 0.f;

    #pragma unroll
    for (int p = 0; p < 3; ++p) {
        __half2 a0 = __float2half2_rn(0.f), a1 = a0, a2 = a0, a3 = a0;
        #pragma unroll
        for (int c = 0; c < 4; ++c) {
            const uint4 v = rv[p * 4 + c];
            const __half2 w = wh[p * 4 + c];
            a0 = __hfma2(*reinterpret_cast<const __half2*>(&v.x), w, a0);
            a1 = __hfma2(*reinterpret_cast<const __half2*>(&v.y), w, a1);
            a2 = __hfma2(*reinterpret_cast<const __half2*>(&v.z), w, a2);
            a3 = __hfma2(*reinterpret_cast<const __half2*>(&v.w), w, a3);
        }
        const float2 f0 = __half22float2(a0);
        const float2 f1 = __half22float2(a1);
        const float2 f2 = __half22float2(a2);
        const float2 f3 = __half22float2(a3);
        accx[0] += f0.x; accx[1] += f0.y;
        accx[2] += f1.x; accx[3] += f1.y;
        accx[4] += f2.x; accx[5] += f2.y;
        accx[6] += f3.x; accx[7] += f3.y;
    }

    constexpr float third = 1.0f / 3.0f;
    f32x4 o0, o1;
    o0.x = accx[0] * third; o0.y = accx[1] * third;
    o0.z = accx[2] * third; o0.w = accx[3] * third;
    o1.x = accx[4] * third; o1.y = accx[5] * third;
    o1.z = accx[6] * third; o1.w = accx[7] * third;

    // Non-temporal 16B stores (keep 256MB output stream out of L3).
    f32x4* op = reinterpret_cast<f32x4*>(out + ((size_t)n * M + m) * Cc);
    __builtin_nontemporal_store(o0, op + quad * 2 + 0);
    __builtin_nontemporal_store(o1, op + quad * 2 + 1);
}

// ---------------------------------------------------------------------------
// Fallback tier: standalone transpose + unsorted fp16 gather (R3 kernels).
// ---------------------------------------------------------------------------
__global__ __launch_bounds__(256) void transpose_chw_hwc_h(
    const float* __restrict__ in, __half* __restrict__ out)
{
    __shared__ float lds[Cc * 257];
    const int slice = blockIdx.y;
    const int pix0  = blockIdx.x * 256;
    const int t     = threadIdx.x;

    const float* src = in + (size_t)slice * Cc * HWPIX + pix0 + t;
    #pragma unroll
    for (int c = 0; c < Cc; ++c)
        lds[c * 257 + t] = src[(size_t)c * HWPIX];
    __syncthreads();

    uint4* dst = reinterpret_cast<uint4*>(
        out + (size_t)slice * HWPIX * Cc + (size_t)pix0 * Cc);
    #pragma unroll
    for (int k = 0; k < 4; ++k) {
        const int idx = k * 256 + t;
        const int pix = idx >> 2;
        const int c0  = (idx & 3) * 8;
        unsigned r[4];
        #pragma unroll
        for (int j = 0; j < 4; ++j) {
            const __half h0 = __float2half(lds[(c0 + 2 * j + 0) * 257 + pix]);
            const __half h1 = __float2half(lds[(c0 + 2 * j + 1) * 257 + pix]);
            r[j] = (unsigned)__half_as_ushort(h0)
                 | ((unsigned)__half_as_ushort(h1) << 16);
        }
        dst[idx] = make_uint4(r[0], r[1], r[2], r[3]);
    }
}

__global__ __launch_bounds__(256) void triplane_gather_hwc8h(
    const __half* __restrict__ tp, const float* __restrict__ coords,
    float* __restrict__ out, int M)
{
    const int gid   = blockIdx.x * 256 + threadIdx.x;
    const int m     = gid >> 3;
    const int chunk = gid & 7;
    const int n     = blockIdx.y;
    if (m >= M) return;

    const float* cp = coords + ((size_t)n * M + m) * 3;
    const float cx = cp[0], cy = cp[1], cz = cp[2];

    const uint2* addr[12];
    float w[12];

    #pragma unroll
    for (int p = 0; p < 3; ++p) {
        const float gxc = (p == 2) ? cz : cx;
        const float gyc = (p == 0) ? cy : ((p == 1) ? cz : cx);
        const float x = ((gxc + 1.0f) * 256.0f - 1.0f) * 0.5f;
        const float y = ((gyc + 1.0f) * 256.0f - 1.0f) * 0.5f;
        const float x0f = floorf(x), y0f = floorf(y);
        const float wx = x - x0f, wy = y - y0f;
        const int x0 = (int)x0f, y0 = (int)y0f;
        const int x1 = x0 + 1,   y1 = y0 + 1;
        const bool vx0 = (unsigned)x0 < 256u;
        const bool vx1 = (unsigned)x1 < 256u;
        const bool vy0 = (unsigned)y0 < 256u;
        const bool vy1 = (unsigned)y1 < 256u;
        const int cx0 = min(max(x0, 0), 255), cx1 = min(max(x1, 0), 255);
        const int cy0 = min(max(y0, 0), 255), cy1 = min(max(y1, 0), 255);

        w[p * 4 + 0] = ((vx0 && vy0) ? 1.f : 0.f) * (1.f - wx) * (1.f - wy);
        w[p * 4 + 1] = ((vx1 && vy0) ? 1.f : 0.f) * wx * (1.f - wy);
        w[p * 4 + 2] = ((vx0 && vy1) ? 1.f : 0.f) * (1.f - wx) * wy;
        w[p * 4 + 3] = ((vx1 && vy1) ? 1.f : 0.f) * wx * wy;

        const uint2* base = reinterpret_cast<const uint2*>(
            tp + (size_t)(n * 3 + p) * HWPIX * Cc);
        addr[p * 4 + 0] = base + (size_t)((cy0 << 8) + cx0) * 8 + chunk;
        addr[p * 4 + 1] = base + (size_t)((cy0 << 8) + cx1) * 8 + chunk;
        addr[p * 4 + 2] = base + (size_t)((cy1 << 8) + cx0) * 8 + chunk;
        addr[p * 4 + 3] = base + (size_t)((cy1 << 8) + cx1) * 8 + chunk;
    }

    uint2 rv[12];
    #pragma unroll
    for (int j = 0; j < 12; ++j) rv[j] = *addr[j];

    float4 acc = make_float4(0.f, 0.f, 0.f, 0.f);
    #pragma unroll
    for (int j = 0; j < 12; ++j) {
        const __half2 h0 = *reinterpret_cast<const __half2*>(&rv[j].x);
        const __half2 h1 = *reinterpret_cast<const __half2*>(&rv[j].y);
        const float2 f0 = __half22float2(h0);
        const float2 f1 = __half22float2(h1);
        acc.x += w[j] * f0.x;
        acc.y += w[j] * f0.y;
        acc.z += w[j] * f1.x;
        acc.w += w[j] * f1.y;
    }

    constexpr float third = 1.0f / 3.0f;
    acc.x *= third; acc.y *= third; acc.z *= third; acc.w *= third;

    float4* op = reinterpret_cast<float4*>(out + ((size_t)n * M + m) * Cc);
    op[chunk] = acc;
}

// ---------------------------------------------------------------------------
// Last-resort fallback (no workspace): gather from [C][H][W] f32 layout.
// ---------------------------------------------------------------------------
__global__ __launch_bounds__(256) void triplane_gather_chw(
    const float* __restrict__ planes, const float* __restrict__ coords,
    float* __restrict__ out, int M)
{
    const int m = blockIdx.x * 256 + threadIdx.x;
    const int n = blockIdx.y;
    if (m >= M) return;

    const float* cp = coords + ((size_t)n * M + m) * 3;
    const float cx = cp[0], cy = cp[1], cz = cp[2];

    int   off[3][4];
    float w[3][4];
    #pragma unroll
    for (int p = 0; p < 3; ++p) {
        const float gxc = (p == 2) ? cz : cx;
        const float gyc = (p == 0) ? cy : ((p == 1) ? cz : cx);
        const float x = ((gxc + 1.0f) * 256.0f - 1.0f) * 0.5f;
        const float y = ((gyc + 1.0f) * 256.0f - 1.0f) * 0.5f;
        const float x0f = floorf(x), y0f = floorf(y);
        const float wx = x - x0f, wy = y - y0f;
        const int x0 = (int)x0f, y0 = (int)y0f;
        const int x1 = x0 + 1,   y1 = y0 + 1;
        const bool vx0 = (unsigned)x0 < 256u, vx1 = (unsigned)x1 < 256u;
        const bool vy0 = (unsigned)y0 < 256u, vy1 = (unsigned)y1 < 256u;
        const int cx0 = min(max(x0, 0), 255), cx1 = min(max(x1, 0), 255);
        const int cy0 = min(max(y0, 0), 255), cy1 = min(max(y1, 0), 255);
        off[p][0] = (cy0 << 8) + cx0;  w[p][0] = ((vx0 && vy0) ? 1.f : 0.f) * (1.f - wx) * (1.f - wy);
        off[p][1] = (cy0 << 8) + cx1;  w[p][1] = ((vx1 && vy0) ? 1.f : 0.f) * wx * (1.f - wy);
        off[p][2] = (cy1 << 8) + cx0;  w[p][2] = ((vx0 && vy1) ? 1.f : 0.f) * (1.f - wx) * wy;
        off[p][3] = (cy1 << 8) + cx1;  w[p][3] = ((vx1 && vy1) ? 1.f : 0.f) * wx * wy;
    }

    float* op = out + ((size_t)n * M + m) * Cc;
    constexpr float third = 1.0f / 3.0f;
    for (int c = 0; c < Cc; ++c) {
        float a = 0.f;
        #pragma unroll
        for (int p = 0; p < 3; ++p) {
            const float* b = planes + ((size_t)(n * 3 + p) * Cc + c) * HWPIX;
            a += w[p][0] * b[off[p][0]] + w[p][1] * b[off[p][1]]
               + w[p][2] * b[off[p][2]] + w[p][3] * b[off[p][3]];
        }
        op[c] = a * third;
    }
}

extern "C" void kernel_launch(void* const* d_in, const int* in_sizes, int n_in,
                              void* d_out, int out_size, void* d_ws, size_t ws_size,
                              hipStream_t stream)
{
    const float* planes = (const float*)d_in[0];
    const float* coords = (const float*)d_in[1];
    float* out = (float*)d_out;

    const int M = in_sizes[1] / (Nn * 3);           // 500000

    auto align256 = [](size_t x) { return (x + 255) & ~(size_t)255; };
    const size_t tph_bytes = align256((size_t)Nn * Pp * HWPIX * Cc * sizeof(__half)); // ~50 MB
    const size_t idx_bytes = align256((size_t)Nn * M * sizeof(unsigned));             // ~8 MB
    const size_t cnt_bytes = align256((size_t)Nn * NCO * sizeof(unsigned));           // 64 KB

    bool done = false;
    if (ws_size >= tph_bytes + idx_bytes + cnt_bytes && M <= NIT * TT) {
        char* p = (char*)d_ws;
        __half*   tp  = (__half*)p;    p += tph_bytes;
        unsigned* idx = (unsigned*)p;  p += idx_bytes;
        unsigned* cnt = (unsigned*)p;

        void* args[] = { (void*)&planes, (void*)&coords, (void*)&tp,
                         (void*)&cnt, (void*)&idx, (void*)&M };
        const hipError_t e = hipLaunchCooperativeKernel(
            (const void*)fused_prep, dim3(GRID), dim3(BLK), args, 0, stream);
        if (e == hipSuccess) {
            const int gx  = (M * 4 + 255) / 256;   // 4 lanes per sample
            const int nwg = Nn * gx;
            triplane_gather4h<<<nwg, 256, 0, stream>>>(tp, idx, coords, out, M, gx, nwg);
            done = true;
        }
    }

    if (!done) {
        if (ws_size >= tph_bytes) {
            __half* tp = (__half*)d_ws;
            transpose_chw_hwc_h<<<dim3(HWPIX / 256, Nn * Pp), 256, 0, stream>>>(planes, tp);
            const int gx = (M * 8 + 255) / 256;
            triplane_gather_hwc8h<<<dim3(gx, Nn), 256, 0, stream>>>(tp, coords, out, M);
        } else {
            const int gx = (M + 255) / 256;
            triplane_gather_chw<<<dim3(gx, Nn), 256, 0, stream>>>(planes, coords, out, M);
        }
    }
}

// Round 14
// 286.095 us; speedup vs baseline: 2.2208x; 2.2208x over previous
//
#include <hip/hip_runtime.h>
#include <hip/hip_fp16.h>

// Tri-plane importance-renderer sampling.
// planes: [N=4][P=3][C=32][H=256][W=256] f32
// coords: [N][M=500000][3] f32, directions unused.
// out:    [N][M][C] f32  = mean over P of bilinear samples (zeros padding,
//                          align_corners=False).
// Plane->grid mapping (from inv(_PLANES)): p0:(cx,cy)  p1:(cx,cz)  p2:(cz,cx)
//
// R13 insight: hipMemsetAsync inside the captured region silently vanished
// from the graph -> replays ran with poisoned (0xAA) counters -> garbage bins
// -> post-timing divergence. R14: zero counters with a plain kernel (proven
// R4-R11), keep R13's structure: zero -> fused{transpose || bin} -> gather
// with BLOCK=CELL. Tail count defensively clamped.

constexpr int Cc = 32, Hh = 256, Ww = 256, Pp = 3, Nn = 4;
constexpr int HWPIX = Hh * Ww;   // 65536
constexpr int NCO   = 4096;      // 16^3 coarse Morton cells
constexpr int CAP   = 256;       // bin capacity (mean 122; overflow ~0, tail-safe)
constexpr int TAILB = 64;        // tail-handling blocks per n
constexpr int TRB   = Nn * Pp * (HWPIX / 256);   // 3072 transpose blocks

typedef float f32x4 __attribute__((ext_vector_type(4)));

__device__ inline unsigned spread3(unsigned x) {
    x &= 0x3FFu;
    x = (x | (x << 16)) & 0x030000FFu;
    x = (x | (x << 8))  & 0x0300F00Fu;
    x = (x | (x << 4))  & 0x030C30C3u;
    x = (x | (x << 2))  & 0x09249249u;
    return x;
}
// 12-bit Morton key from 4 bits/axis.
__device__ inline unsigned coarse_key(float cx, float cy, float cz) {
    const int a = min(max((int)((cx + 1.0f) * 8.0f), 0), 15);
    const int b = min(max((int)((cy + 1.0f) * 8.0f), 0), 15);
    const int c = min(max((int)((cz + 1.0f) * 8.0f), 0), 15);
    return spread3((unsigned)a) | (spread3((unsigned)b) << 1) | (spread3((unsigned)c) << 2);
}

__global__ __launch_bounds__(256) void zero_u32(unsigned* __restrict__ p, int n)
{
    const int i = blockIdx.x * 256 + threadIdx.x;
    if (i < n) p[i] = 0u;
}

// ---------------------------------------------------------------------------
// K1: fused transpose || binning. Blocks < TRB transpose one 256-pixel tile
// (f32 CHW -> fp16 HWC); the rest bin one 256-sample chunk of one n.
// Roles are data-independent -> no sync needed; CUs overlap them.
// ---------------------------------------------------------------------------
__global__ __launch_bounds__(256) void fused_tb(
    const float* __restrict__ planes, const float* __restrict__ coords,
    __half* __restrict__ tp, unsigned* __restrict__ count,
    unsigned* __restrict__ tailcnt, unsigned* __restrict__ bin,
    unsigned* __restrict__ tail, int M, int binBlocksPerN)
{
    __shared__ float lds[Cc * 257];   // used by transpose role only
    const int t = threadIdx.x;

    if (blockIdx.x < TRB) {
        const int slice = blockIdx.x >> 8;           // 256 tiles per slice
        const int pix0  = (blockIdx.x & 255) * 256;

        const float* src = planes + (size_t)slice * Cc * HWPIX + pix0 + t;
        #pragma unroll
        for (int c = 0; c < Cc; ++c)
            lds[c * 257 + t] = src[(size_t)c * HWPIX];
        __syncthreads();

        uint4* dst = reinterpret_cast<uint4*>(
            tp + (size_t)slice * HWPIX * Cc + (size_t)pix0 * Cc);
        #pragma unroll
        for (int k = 0; k < 4; ++k) {
            const int idx = k * 256 + t;
            const int pix = idx >> 2;        // 4 uint4 per pixel
            const int c0  = (idx & 3) * 8;   // 8 channels per uint4
            unsigned r[4];
            #pragma unroll
            for (int j = 0; j < 4; ++j) {
                const __half h0 = __float2half(lds[(c0 + 2 * j + 0) * 257 + pix]);
                const __half h1 = __float2half(lds[(c0 + 2 * j + 1) * 257 + pix]);
                r[j] = (unsigned)__half_as_ushort(h0)
                     | ((unsigned)__half_as_ushort(h1) << 16);
            }
            dst[idx] = make_uint4(r[0], r[1], r[2], r[3]);
        }
    } else {
        const int j = blockIdx.x - TRB;
        const int n = j / binBlocksPerN;
        const int m = (j - n * binBlocksPerN) * 256 + t;
        if (m < M) {
            const float* cp = coords + ((size_t)n * M + m) * 3;
            const unsigned k = coarse_key(cp[0], cp[1], cp[2]);
            const unsigned r = atomicAdd(&count[n * NCO + k], 1u);
            if (r < CAP) {
                bin[(((size_t)n * NCO + k) << 8) + r] = (unsigned)m;
            } else {
                const unsigned tt = atomicAdd(&tailcnt[n], 1u);
                tail[(size_t)n * M + tt] = (unsigned)m;
            }
        }
    }
}

// ---------------------------------------------------------------------------
// One sample: R8's proven body. 4 lanes/sample, lane reads uint4 #quad of
// each of 12 corners; packed __hfma2 per plane, f32 cross-plane; nt-stores.
// ---------------------------------------------------------------------------
__device__ __forceinline__ void gather_one(
    const __half* __restrict__ tp, const float* __restrict__ coords,
    float* __restrict__ out, int n, int m, int quad, int M)
{
    const float* cp = coords + ((size_t)n * M + m) * 3;
    const float cx = cp[0], cy = cp[1], cz = cp[2];

    const uint4* addr[12];
    __half2 wh[12];

    #pragma unroll
    for (int p = 0; p < 3; ++p) {
        const float gxc = (p == 2) ? cz : cx;
        const float gyc = (p == 0) ? cy : ((p == 1) ? cz : cx);
        // exact reference op order: ((g+1)*S - 1) * 0.5
        const float x = ((gxc + 1.0f) * 256.0f - 1.0f) * 0.5f;
        const float y = ((gyc + 1.0f) * 256.0f - 1.0f) * 0.5f;
        const float x0f = floorf(x), y0f = floorf(y);
        const float wx = x - x0f, wy = y - y0f;
        const int x0 = (int)x0f, y0 = (int)y0f;
        const int x1 = x0 + 1,   y1 = y0 + 1;
        const bool vx0 = (unsigned)x0 < 256u;
        const bool vx1 = (unsigned)x1 < 256u;
        const bool vy0 = (unsigned)y0 < 256u;
        const bool vy1 = (unsigned)y1 < 256u;
        const int cx0 = min(max(x0, 0), 255), cx1 = min(max(x1, 0), 255);
        const int cy0 = min(max(y0, 0), 255), cy1 = min(max(y1, 0), 255);

        const float w00 = ((vx0 && vy0) ? 1.f : 0.f) * (1.f - wx) * (1.f - wy);
        const float w10 = ((vx1 && vy0) ? 1.f : 0.f) * wx * (1.f - wy);
        const float w01 = ((vx0 && vy1) ? 1.f : 0.f) * (1.f - wx) * wy;
        const float w11 = ((vx1 && vy1) ? 1.f : 0.f) * wx * wy;
        wh[p * 4 + 0] = __float2half2_rn(w00);
        wh[p * 4 + 1] = __float2half2_rn(w10);
        wh[p * 4 + 2] = __float2half2_rn(w01);
        wh[p * 4 + 3] = __float2half2_rn(w11);

        const uint4* base = reinterpret_cast<const uint4*>(
            tp + (size_t)(n * 3 + p) * HWPIX * Cc);
        addr[p * 4 + 0] = base + (size_t)((cy0 << 8) + cx0) * 4 + quad;
        addr[p * 4 + 1] = base + (size_t)((cy0 << 8) + cx1) * 4 + quad;
        addr[p * 4 + 2] = base + (size_t)((cy1 << 8) + cx0) * 4 + quad;
        addr[p * 4 + 3] = base + (size_t)((cy1 << 8) + cx1) * 4 + quad;
    }

    uint4 rv[12];
    #pragma unroll
    for (int j = 0; j < 12; ++j) rv[j] = *addr[j];

    float accx[8];
    #pragma unroll
    for (int i = 0; i < 8; ++i) accx[i] = 0.f;

    #pragma unroll
    for (int p = 0; p < 3; ++p) {
        __half2 a0 = __float2half2_rn(0.f), a1 = a0, a2 = a0, a3 = a0;
        #pragma unroll
        for (int c = 0; c < 4; ++c) {
            const uint4 v = rv[p * 4 + c];
            const __half2 w = wh[p * 4 + c];
            a0 = __hfma2(*reinterpret_cast<const __half2*>(&v.x), w, a0);
            a1 = __hfma2(*reinterpret_cast<const __half2*>(&v.y), w, a1);
            a2 = __hfma2(*reinterpret_cast<const __half2*>(&v.z), w, a2);
            a3 = __hfma2(*reinterpret_cast<const __half2*>(&v.w), w, a3);
        }
        const float2 f0 = __half22float2(a0);
        const float2 f1 = __half22float2(a1);
        const float2 f2 = __half22float2(a2);
        const float2 f3 = __half22float2(a3);
        accx[0] += f0.x; accx[1] += f0.y;
        accx[2] += f1.x; accx[3] += f1.y;
        accx[4] += f2.x; accx[5] += f2.y;
        accx[6] += f3.x; accx[7] += f3.y;
    }

    constexpr float third = 1.0f / 3.0f;
    f32x4 o0, o1;
    o0.x = accx[0] * third; o0.y = accx[1] * third;
    o0.z = accx[2] * third; o0.w = accx[3] * third;
    o1.x = accx[4] * third; o1.y = accx[5] * third;
    o1.z = accx[6] * third; o1.w = accx[7] * third;

    f32x4* op = reinterpret_cast<f32x4*>(out + ((size_t)n * M + m) * Cc);
    __builtin_nontemporal_store(o0, op + quad * 2 + 0);
    __builtin_nontemporal_store(o1, op + quad * 2 + 1);
}

// ---------------------------------------------------------------------------
// K2: gather, BLOCK = CELL. 256 threads = 64 samples/iteration; loop over the
// cell's count. Tail blocks grid-stride the (normally empty) overflow list.
// Consecutive blocks = consecutive Morton cells; bijective XCD chunk swizzle.
// ---------------------------------------------------------------------------
__global__ __launch_bounds__(256) void gather_cells(
    const __half* __restrict__ tp, const unsigned* __restrict__ count,
    const unsigned* __restrict__ tailcnt, const unsigned* __restrict__ bin,
    const unsigned* __restrict__ tail, const float* __restrict__ coords,
    float* __restrict__ out, int M, int nwg)
{
    int bid = blockIdx.x;
    {   // bijective chunked XCD swizzle (m204 form)
        const int q = nwg >> 3, r = nwg & 7;
        const int xcd = bid & 7, i = bid >> 3;
        bid = (xcd < r ? xcd * (q + 1) : r * (q + 1) + (xcd - r) * q) + i;
    }
    constexpr int PER_N = NCO + TAILB;
    const int n  = bid / PER_N;
    const int cb = bid - n * PER_N;
    const int t  = threadIdx.x;
    const int ls = t >> 2;          // sample lane within 64-sample batch
    const int quad = t & 3;

    if (cb < NCO) {
        unsigned c = count[n * NCO + cb];
        c = (c > (unsigned)CAP) ? (unsigned)CAP : c;
        const unsigned* bp = bin + (((size_t)n * NCO + cb) << 8);
        for (unsigned base = 0; base < c; base += 64) {
            const unsigned j = base + ls;
            if (j < c)
                gather_one(tp, coords, out, n, (int)bp[j], quad, M);
        }
    } else {
        unsigned tc = tailcnt[n];
        if (tc > (unsigned)M) tc = (unsigned)M;   // defensive clamp
        for (unsigned s = (unsigned)(cb - NCO) * 64 + ls; s < tc;
             s += (unsigned)TAILB * 64)
            gather_one(tp, coords, out, n, (int)tail[(size_t)n * M + s], quad, M);
    }
}

// ---------------------------------------------------------------------------
// Fallback tier: standalone transpose + unsorted fp16 gather (R3 kernels).
// ---------------------------------------------------------------------------
__global__ __launch_bounds__(256) void transpose_chw_hwc_h(
    const float* __restrict__ in, __half* __restrict__ out)
{
    __shared__ float lds[Cc * 257];
    const int slice = blockIdx.y;
    const int pix0  = blockIdx.x * 256;
    const int t     = threadIdx.x;

    const float* src = in + (size_t)slice * Cc * HWPIX + pix0 + t;
    #pragma unroll
    for (int c = 0; c < Cc; ++c)
        lds[c * 257 + t] = src[(size_t)c * HWPIX];
    __syncthreads();

    uint4* dst = reinterpret_cast<uint4*>(
        out + (size_t)slice * HWPIX * Cc + (size_t)pix0 * Cc);
    #pragma unroll
    for (int k = 0; k < 4; ++k) {
        const int idx = k * 256 + t;
        const int pix = idx >> 2;
        const int c0  = (idx & 3) * 8;
        unsigned r[4];
        #pragma unroll
        for (int j = 0; j < 4; ++j) {
            const __half h0 = __float2half(lds[(c0 + 2 * j + 0) * 257 + pix]);
            const __half h1 = __float2half(lds[(c0 + 2 * j + 1) * 257 + pix]);
            r[j] = (unsigned)__half_as_ushort(h0)
                 | ((unsigned)__half_as_ushort(h1) << 16);
        }
        dst[idx] = make_uint4(r[0], r[1], r[2], r[3]);
    }
}

__global__ __launch_bounds__(256) void triplane_gather_hwc8h(
    const __half* __restrict__ tp, const float* __restrict__ coords,
    float* __restrict__ out, int M)
{
    const int gid   = blockIdx.x * 256 + threadIdx.x;
    const int m     = gid >> 3;
    const int chunk = gid & 7;
    const int n     = blockIdx.y;
    if (m >= M) return;

    const float* cp = coords + ((size_t)n * M + m) * 3;
    const float cx = cp[0], cy = cp[1], cz = cp[2];

    const uint2* addr[12];
    float w[12];

    #pragma unroll
    for (int p = 0; p < 3; ++p) {
        const float gxc = (p == 2) ? cz : cx;
        const float gyc = (p == 0) ? cy : ((p == 1) ? cz : cx);
        const float x = ((gxc + 1.0f) * 256.0f - 1.0f) * 0.5f;
        const float y = ((gyc + 1.0f) * 256.0f - 1.0f) * 0.5f;
        const float x0f = floorf(x), y0f = floorf(y);
        const float wx = x - x0f, wy = y - y0f;
        const int x0 = (int)x0f, y0 = (int)y0f;
        const int x1 = x0 + 1,   y1 = y0 + 1;
        const bool vx0 = (unsigned)x0 < 256u;
        const bool vx1 = (unsigned)x1 < 256u;
        const bool vy0 = (unsigned)y0 < 256u;
        const bool vy1 = (unsigned)y1 < 256u;
        const int cx0 = min(max(x0, 0), 255), cx1 = min(max(x1, 0), 255);
        const int cy0 = min(max(y0, 0), 255), cy1 = min(max(y1, 0), 255);

        w[p * 4 + 0] = ((vx0 && vy0) ? 1.f : 0.f) * (1.f - wx) * (1.f - wy);
        w[p * 4 + 1] = ((vx1 && vy0) ? 1.f : 0.f) * wx * (1.f - wy);
        w[p * 4 + 2] = ((vx0 && vy1) ? 1.f : 0.f) * (1.f - wx) * wy;
        w[p * 4 + 3] = ((vx1 && vy1) ? 1.f : 0.f) * wx * wy;

        const uint2* base = reinterpret_cast<const uint2*>(
            tp + (size_t)(n * 3 + p) * HWPIX * Cc);
        addr[p * 4 + 0] = base + (size_t)((cy0 << 8) + cx0) * 8 + chunk;
        addr[p * 4 + 1] = base + (size_t)((cy0 << 8) + cx1) * 8 + chunk;
        addr[p * 4 + 2] = base + (size_t)((cy1 << 8) + cx0) * 8 + chunk;
        addr[p * 4 + 3] = base + (size_t)((cy1 << 8) + cx1) * 8 + chunk;
    }

    uint2 rv[12];
    #pragma unroll
    for (int j = 0; j < 12; ++j) rv[j] = *addr[j];

    float4 acc = make_float4(0.f, 0.f, 0.f, 0.f);
    #pragma unroll
    for (int j = 0; j < 12; ++j) {
        const __half2 h0 = *reinterpret_cast<const __half2*>(&rv[j].x);
        const __half2 h1 = *reinterpret_cast<const __half2*>(&rv[j].y);
        const float2 f0 = __half22float2(h0);
        const float2 f1 = __half22float2(h1);
        acc.x += w[j] * f0.x;
        acc.y += w[j] * f0.y;
        acc.z += w[j] * f1.x;
        acc.w += w[j] * f1.y;
    }

    constexpr float third = 1.0f / 3.0f;
    acc.x *= third; acc.y *= third; acc.z *= third; acc.w *= third;

    float4* op = reinterpret_cast<float4*>(out + ((size_t)n * M + m) * Cc);
    op[chunk] = acc;
}

// ---------------------------------------------------------------------------
// Last-resort fallback (no workspace): gather from [C][H][W] f32 layout.
// ---------------------------------------------------------------------------
__global__ __launch_bounds__(256) void triplane_gather_chw(
    const float* __restrict__ planes, const float* __restrict__ coords,
    float* __restrict__ out, int M)
{
    const int m = blockIdx.x * 256 + threadIdx.x;
    const int n = blockIdx.y;
    if (m >= M) return;

    const float* cp = coords + ((size_t)n * M + m) * 3;
    const float cx = cp[0], cy = cp[1], cz = cp[2];

    int   off[3][4];
    float w[3][4];
    #pragma unroll
    for (int p = 0; p < 3; ++p) {
        const float gxc = (p == 2) ? cz : cx;
        const float gyc = (p == 0) ? cy : ((p == 1) ? cz : cx);
        const float x = ((gxc + 1.0f) * 256.0f - 1.0f) * 0.5f;
        const float y = ((gyc + 1.0f) * 256.0f - 1.0f) * 0.5f;
        const float x0f = floorf(x), y0f = floorf(y);
        const float wx = x - x0f, wy = y - y0f;
        const int x0 = (int)x0f, y0 = (int)y0f;
        const int x1 = x0 + 1,   y1 = y0 + 1;
        const bool vx0 = (unsigned)x0 < 256u, vx1 = (unsigned)x1 < 256u;
        const bool vy0 = (unsigned)y0 < 256u, vy1 = (unsigned)y1 < 256u;
        const int cx0 = min(max(x0, 0), 255), cx1 = min(max(x1, 0), 255);
        const int cy0 = min(max(y0, 0), 255), cy1 = min(max(y1, 0), 255);
        off[p][0] = (cy0 << 8) + cx0;  w[p][0] = ((vx0 && vy0) ? 1.f : 0.f) * (1.f - wx) * (1.f - wy);
        off[p][1] = (cy0 << 8) + cx1;  w[p][1] = ((vx1 && vy0) ? 1.f : 0.f) * wx * (1.f - wy);
        off[p][2] = (cy1 << 8) + cx0;  w[p][2] = ((vx0 && vy1) ? 1.f : 0.f) * (1.f - wx) * wy;
        off[p][3] = (cy1 << 8) + cx1;  w[p][3] = ((vx1 && vy1) ? 1.f : 0.f) * wx * wy;
    }

    float* op = out + ((size_t)n * M + m) * Cc;
    constexpr float third = 1.0f / 3.0f;
    for (int c = 0; c < Cc; ++c) {
        float a = 0.f;
        #pragma unroll
        for (int p = 0; p < 3; ++p) {
            const float* b = planes + ((size_t)(n * 3 + p) * Cc + c) * HWPIX;
            a += w[p][0] * b[off[p][0]] + w[p][1] * b[off[p][1]]
               + w[p][2] * b[off[p][2]] + w[p][3] * b[off[p][3]];
        }
        op[c] = a * third;
    }
}

extern "C" void kernel_launch(void* const* d_in, const int* in_sizes, int n_in,
                              void* d_out, int out_size, void* d_ws, size_t ws_size,
                              hipStream_t stream)
{
    const float* planes = (const float*)d_in[0];
    const float* coords = (const float*)d_in[1];
    float* out = (float*)d_out;

    const int M = in_sizes[1] / (Nn * 3);           // 500000

    auto align256 = [](size_t x) { return (x + 255) & ~(size_t)255; };
    const size_t tph_bytes  = align256((size_t)Nn * Pp * HWPIX * Cc * sizeof(__half)); // ~50 MB
    const size_t bin_bytes  = align256((size_t)Nn * NCO * CAP * sizeof(unsigned));     // ~16.8 MB
    const size_t tail_bytes = align256((size_t)Nn * M * sizeof(unsigned));             // ~8 MB
    const size_t cnt_bytes  = align256((size_t)Nn * NCO * sizeof(unsigned));           // 64 KB
    const size_t tc_bytes   = align256((size_t)Nn * sizeof(unsigned));                 // 256 B

    if (ws_size >= tph_bytes + bin_bytes + tail_bytes + cnt_bytes + tc_bytes) {
        char* p = (char*)d_ws;
        __half*   tp      = (__half*)p;   p += tph_bytes;
        unsigned* bin     = (unsigned*)p; p += bin_bytes;
        unsigned* tail    = (unsigned*)p; p += tail_bytes;
        unsigned* count   = (unsigned*)p; p += cnt_bytes;
        unsigned* tailcnt = (unsigned*)p;

        // Zero counters with a plain kernel (hipMemsetAsync silently dropped
        // from the captured graph in R13 -> replay corruption).
        const int nz = Nn * NCO + Nn;   // count[] + tailcnt[] (contiguous)
        zero_u32<<<(nz + 255) / 256, 256, 0, stream>>>(count, nz);

        const int binBlocksPerN = (M + 255) / 256;
        const int k1 = TRB + Nn * binBlocksPerN;
        fused_tb<<<k1, 256, 0, stream>>>(planes, coords, tp, count, tailcnt,
                                         bin, tail, M, binBlocksPerN);

        const int nwg = Nn * (NCO + TAILB);
        gather_cells<<<nwg, 256, 0, stream>>>(tp, count, tailcnt, bin, tail,
                                              coords, out, M, nwg);
    } else if (ws_size >= tph_bytes) {
        __half* tp = (__half*)d_ws;
        transpose_chw_hwc_h<<<dim3(HWPIX / 256, Nn * Pp), 256, 0, stream>>>(planes, tp);
        const int gx = (M * 8 + 255) / 256;
        triplane_gather_hwc8h<<<dim3(gx, Nn), 256, 0, stream>>>(tp, coords, out, M);
    } else {
        const int gx = (M + 255) / 256;
        triplane_gather_chw<<<dim3(gx, Nn), 256, 0, stream>>>(planes, coords, out, M);
    }
}